// Round 9
// baseline (691.330 us; speedup 1.0000x reference)
//
#include <hip/hip_runtime.h>
#include <math.h>

#define N_TOK 16384
#define DDIM  384
#define KCODE 8192
#define EMA   0.99f
#define EPS_F 1e-5f
#define MARGIN 0.5f
#define NB 32            // KCODE / 256 code-blocks in coarse pass

typedef _Float16 f16x8 __attribute__((ext_vector_type(8)));
typedef float    f32x4 __attribute__((ext_vector_type(4)));

// ---- ws byte offsets (total <= proven 13,041,672 B) ----
#define OFF_PD1    0UL        // [NB][N_TOK] f32 coarse best dist
#define OFF_PI1    2097152UL  // [NB][N_TOK] i32 coarse best idx
#define OFF_PD2    4194304UL  // [NB][N_TOK] f32 coarse 2nd dist
#define OFF_CBH    6291456UL  // [KCODE*DDIM] f16 pre-converted codebook
#define OFF_TOKL   0UL        // phase3: [N_TOK] i32 tokens bucketed by code
#define OFF_OFFS   65536UL    // phase3: [KCODE+1] i32 segment offsets
#define OFF_CURS   98560UL    // phase3: [KCODE] i32 fill cursors
// outside region A:
#define OFF_WSIDX  12582912UL // [N_TOK] i32
#define OFF_COUNTS 12648448UL // [KCODE] f32
#define OFF_SUMSQ  12681216UL // f32 (unused, in zeroed range)
#define OFF_NACC   12681220UL // f32 (+pad to 12681472)
#define OFF_CNORM  12681472UL // [KCODE] f32
#define OFF_FLIST  12714240UL // [N_TOK] i32 flagged tokens
#define OFF_FCNT   12779776UL // i32 + pad to 12780032
#define OFF_PSUM   12780032UL // [4096] f32 per-block commitment partials -> 12796416
#define OFF_FD1    12796416UL // [N_TOK] f32 global f16-best dist per token -> 12861952

// async global->LDS, 16B per lane; dest = wave-uniform base + lane*16
typedef __attribute__((address_space(1))) const unsigned int gas_uint;
typedef __attribute__((address_space(3))) unsigned int       las_uint;
__device__ __forceinline__ void gload_lds16(const void* g, void* l) {
    __builtin_amdgcn_global_load_lds((gas_uint*)g, (las_uint*)l, 16, 0, 0);
}

__global__ void cnorm_kernel(const float* __restrict__ cb, float* __restrict__ cnorm) {
    int wave = (blockIdx.x * blockDim.x + threadIdx.x) >> 6;
    int lane = threadIdx.x & 63;
    if (wave >= KCODE) return;
    const float* row = cb + (size_t)wave * DDIM;
    float s = 0.f;
    #pragma unroll
    for (int r = 0; r < 6; r++) { float v = row[lane + 64 * r]; s += v * v; }
    #pragma unroll
    for (int off = 32; off > 0; off >>= 1) s += __shfl_down(s, off, 64);
    if (lane == 0) cnorm[wave] = s;
}

// one-shot fp32 -> f16 conversion of z (into out_q scratch) and cb (into ws).
__global__ void convert_kernel(const float* __restrict__ z, const float* __restrict__ cb,
                               _Float16* __restrict__ zh, _Float16* __restrict__ cbh) {
    size_t e = ((size_t)blockIdx.x * blockDim.x + threadIdx.x) * 8;
    const size_t NZ = (size_t)N_TOK * DDIM;
    const float* s;
    _Float16* d;
    if (e < NZ) { s = z + e; d = zh + e; }
    else        { s = cb + (e - NZ); d = cbh + (e - NZ); }
    float4 v0 = *(const float4*)(s);
    float4 v1 = *(const float4*)(s + 4);
    f16x8 h;
    h[0]=(_Float16)v0.x; h[1]=(_Float16)v0.y; h[2]=(_Float16)v0.z; h[3]=(_Float16)v0.w;
    h[4]=(_Float16)v1.x; h[5]=(_Float16)v1.y; h[6]=(_Float16)v1.z; h[7]=(_Float16)v1.w;
    *(f16x8*)d = h;
}

// ---- coarse pass: f16 MFMA GEMM (z . c^T), per-token top-2 over 256-code blocks ----
// tile 128x256, BK=32, 8 waves. T3 2-phase prefetch: double-buffered LDS; issue next
// tile's global_load_lds BEFORE current tile's ds_read+MFMA; ONE barrier per iter.
// Prefetch loads get the whole compute phase (~600+ cyc) in flight before the
// vmcnt(0) drain, instead of stalling cold at the barrier.
// Swizzle (round-4-verified): rows 64B = 4x16B chunks, slot = chunk ^ ((row>>1)&3);
// linear LDS dest + pre-permuted global source + XOR'd fragment reads.
// Epilogue xd/xi arrays ALIAS the A buffers (dead after the K loop) -> 48KB total.
__launch_bounds__(512)
__global__ void argmin16_kernel(const _Float16* __restrict__ zh, const _Float16* __restrict__ cbh,
                                const float* __restrict__ cnorm,
                                float* __restrict__ pd1, int* __restrict__ pi1,
                                float* __restrict__ pd2) {
    __shared__ _Float16 As[2][128 * 32];   // 2 x 8 KB (epilogue aliases this)
    __shared__ _Float16 Bs[2][256 * 32];   // 2 x 16 KB

    const int tid  = threadIdx.x;
    const int lane = tid & 63;
    const int wv   = tid >> 6;
    const int wy   = wv >> 2;
    const int wx   = wv & 3;
    const int m0   = blockIdx.x * 128;
    const int n0   = blockIdx.y * 256;
    const int l15  = lane & 15;
    const int l4   = lane >> 4;
    const int csw  = (l15 >> 1) & 3;    // (row>>1)&3 seen by fragment reads

    f32x4 acc[4][4];
    #pragma unroll
    for (int i = 0; i < 4; i++)
        #pragma unroll
        for (int j = 0; j < 4; j++) acc[i][j] = (f32x4){0.f, 0.f, 0.f, 0.f};

    // staging: thread q writes LDS byte q*16 -> row q>>2, slot-chunk q&3.
    // source chunk j = (q&3) ^ ((q>>3)&3)   (row = q>>2)
    const int arow = tid >> 2;
    const int jch  = (tid & 3) ^ ((tid >> 3) & 3);
    const _Float16* a_src  = zh  + (size_t)(m0 + arow) * DDIM + jch * 8;
    const _Float16* b_src0 = cbh + (size_t)(n0 + arow) * DDIM + jch * 8;          // q = tid
    const _Float16* b_src1 = cbh + (size_t)(n0 + 128 + arow) * DDIM + jch * 8;    // q = tid+512
    const int dofs = wv * 512;     // wave-uniform LDS element base

    // prologue: stage tile 0 into buffer 0, drain, barrier
    gload_lds16(a_src,  &As[0][dofs]);
    gload_lds16(b_src0, &Bs[0][dofs]);
    gload_lds16(b_src1, &Bs[0][dofs + 4096]);
    __syncthreads();

    int cur = 0;
    for (int it = 0; it < 12; it++) {
        // phase 1: issue next tile's staging FIRST (lands during compute)
        if (it < 11) {
            int kc = (it + 1) * 32;
            gload_lds16(a_src + kc,  &As[cur ^ 1][dofs]);
            gload_lds16(b_src0 + kc, &Bs[cur ^ 1][dofs]);
            gload_lds16(b_src1 + kc, &Bs[cur ^ 1][dofs + 4096]);
        }
        // phase 2: compute current buffer
        f16x8 af[4], bf[4];
        #pragma unroll
        for (int im = 0; im < 4; im++)
            af[im] = *(const f16x8*)(&As[cur][(wy * 64 + im * 16 + l15) * 32 + (l4 ^ csw) * 8]);
        #pragma unroll
        for (int in = 0; in < 4; in++)
            bf[in] = *(const f16x8*)(&Bs[cur][(wx * 64 + in * 16 + l15) * 32 + (l4 ^ csw) * 8]);
        #pragma unroll
        for (int im = 0; im < 4; im++)
            #pragma unroll
            for (int in = 0; in < 4; in++)
                acc[im][in] = __builtin_amdgcn_mfma_f32_16x16x32_f16(af[im], bf[in], acc[im][in], 0, 0, 0);
        // one drain+barrier per iter (readers of buf cur are done; buf cur^1 staged)
        __syncthreads();
        cur ^= 1;
    }

    // epilogue scratch aliases As (dead after loop; the loop's final barrier protects)
    float* xd1 = (float*)&As[0][0];          // 512 f32 = 2KB
    float* xd2 = xd1 + 512;                  // 2KB
    int*   xi1 = (int*)(xd1 + 1024);         // 2KB

    // dist = ||c||^2 - 2 z.c ; per-token top-2. C/D: col=lane&15, row=(lane>>4)*4+reg
    float cn[4]; int cid[4];
    #pragma unroll
    for (int in = 0; in < 4; in++) {
        cid[in] = n0 + wx * 64 + in * 16 + l15;
        cn[in] = cnorm[cid[in]];
    }
    #pragma unroll
    for (int im = 0; im < 4; im++) {
        #pragma unroll
        for (int reg = 0; reg < 4; reg++) {
            float d1 = cn[0] - 2.f * acc[im][0][reg];
            int   i1 = cid[0];
            float d2 = 3.4e38f;
            #pragma unroll
            for (int in = 1; in < 4; in++) {
                float dd = cn[in] - 2.f * acc[im][in][reg];
                if (dd < d1) { d2 = d1; d1 = dd; i1 = cid[in]; }
                else d2 = fminf(d2, dd);
            }
            #pragma unroll
            for (int off = 1; off < 16; off <<= 1) {
                float od1 = __shfl_xor(d1, off, 16);
                int   oi1 = __shfl_xor(i1, off, 16);
                float od2 = __shfl_xor(d2, off, 16);
                if (od1 < d1 || (od1 == d1 && oi1 < i1)) { d2 = fminf(d1, od2); d1 = od1; i1 = oi1; }
                else d2 = fminf(d2, od1);
            }
            if (l15 == 0) {
                int tl = wy * 64 + im * 16 + l4 * 4 + reg;
                xd1[tl * 4 + wx] = d1; xi1[tl * 4 + wx] = i1; xd2[tl * 4 + wx] = d2;
            }
        }
    }
    __syncthreads();
    if (tid < 128) {
        float d1 = xd1[tid * 4], d2 = xd2[tid * 4];
        int   i1 = xi1[tid * 4];
        #pragma unroll
        for (int x = 1; x < 4; x++) {
            float od1 = xd1[tid * 4 + x], od2 = xd2[tid * 4 + x];
            int   oi1 = xi1[tid * 4 + x];
            if (od1 < d1 || (od1 == d1 && oi1 < i1)) { d2 = fminf(d1, od2); d1 = od1; i1 = oi1; }
            else d2 = fminf(d2, od1);
        }
        size_t o = (size_t)blockIdx.y * N_TOK + m0 + tid;
        pd1[o] = d1; pi1[o] = i1; pd2[o] = d2;
    }
}

// merge 32 coarse partials per token; flag near-ties; record global f16-best dist
__global__ void topmerge_kernel(const float* __restrict__ pd1, const int* __restrict__ pi1,
                                const float* __restrict__ pd2,
                                int* __restrict__ ws_idx, float* __restrict__ out_idx,
                                int* __restrict__ fcnt, int* __restrict__ flist,
                                float* __restrict__ fd1) {
    int t = blockIdx.x * blockDim.x + threadIdx.x;
    if (t >= N_TOK) return;
    float d1 = pd1[t], d2 = pd2[t];
    int   i1 = pi1[t];
    for (int nb = 1; nb < NB; nb++) {
        size_t o = (size_t)nb * N_TOK + t;
        float od1 = pd1[o], od2 = pd2[o];
        int   oi1 = pi1[o];
        if (od1 < d1 || (od1 == d1 && oi1 < i1)) { d2 = fminf(d1, od2); d1 = od1; i1 = oi1; }
        else d2 = fminf(d2, od1);
    }
    ws_idx[t] = i1;
    out_idx[t] = (float)i1;
    fd1[t] = d1;
    if (d2 - d1 < MARGIN) {
        int s = atomicAdd(fcnt, 1);
        flist[s] = t;
    }
}

// band-limited exact rescore: one WAVE per flagged token; only code-blocks whose
// coarse minimum lies within [d1, d1+MARGIN] can contain the exact argmin.
__launch_bounds__(256)
__global__ void rescore2_kernel(const float* __restrict__ z, const float* __restrict__ cb,
                                const float* __restrict__ cnorm,
                                const float* __restrict__ pd1, const float* __restrict__ fd1,
                                const int* __restrict__ flist, const int* __restrict__ fcnt,
                                int* __restrict__ ws_idx, float* __restrict__ out_idx) {
    __shared__ float zt[4 * 384];       // per-wave private z row (no cross-wave sync!)
    const int lane = threadIdx.x & 63;
    const int wv   = threadIdx.x >> 6;
    const int count = fcnt[0];
    float* zrow = zt + wv * 384;
    for (int slot = blockIdx.x * 4 + wv; slot < count; slot += 2048 * 4) {
        int t = flist[slot];
        const float* zr = z + (size_t)t * DDIM;
        #pragma unroll
        for (int r = 0; r < 6; r++) zrow[lane + 64 * r] = zr[lane + 64 * r];
        float band = fd1[t] + MARGIN;
        float bd = 3.4e38f; int bi = 0x7fffffff;
        for (int nb = 0; nb < NB; nb++) {
            if (pd1[(size_t)nb * N_TOK + t] >= band) continue;
            #pragma unroll
            for (int c4 = 0; c4 < 4; c4++) {
                int c = nb * 256 + c4 * 64 + lane;
                const float* cr = cb + (size_t)c * DDIM;
                float a = 0.f;
                for (int d4 = 0; d4 < 96; d4++) {
                    float4 cv = *(const float4*)(cr + d4 * 4);
                    float4 zv = *(const float4*)(zrow + d4 * 4);   // LDS broadcast
                    a = fmaf(zv.x, cv.x, a);
                    a = fmaf(zv.y, cv.y, a);
                    a = fmaf(zv.z, cv.z, a);
                    a = fmaf(zv.w, cv.w, a);
                }
                float dd = cnorm[c] - 2.f * a;
                if (dd < bd) { bd = dd; bi = c; }
            }
        }
        #pragma unroll
        for (int off = 32; off > 0; off >>= 1) {
            float od = __shfl_xor(bd, off, 64);
            int   oi = __shfl_xor(bi, off, 64);
            if (od < bd || (od == bd && oi < bi)) { bd = od; bi = oi; }
        }
        if (lane == 0) { ws_idx[t] = bi; out_idx[t] = (float)bi; }
    }
}

// per-token: gather quantized row, commitment partial (per-BLOCK), counts.
__global__ void quantize_kernel(const float* __restrict__ z, const float* __restrict__ cb,
                                const int* __restrict__ ws_idx,
                                float* __restrict__ out_q,
                                float* __restrict__ counts, float* __restrict__ psum) {
    __shared__ float sm[4];
    int t = (blockIdx.x * blockDim.x + threadIdx.x) >> 6;
    int lane = threadIdx.x & 63, wv = threadIdx.x >> 6;
    int k = ws_idx[t];
    const float* zr = z + (size_t)t * DDIM;
    const float* cr = cb + (size_t)k * DDIM;
    float* qr = out_q + (size_t)t * DDIM;
    float s = 0.f;
    #pragma unroll
    for (int r = 0; r < 6; r++) {
        int d = lane + 64 * r;
        float zv = zr[d];
        float qv = cr[d];
        qr[d] = qv;
        float df = zv - qv;
        s += df * df;
    }
    #pragma unroll
    for (int off = 32; off > 0; off >>= 1) s += __shfl_down(s, off, 64);
    if (lane == 0) {
        sm[wv] = s;
        atomicAdd(counts + k, 1.0f);
    }
    __syncthreads();
    if (threadIdx.x == 0) psum[blockIdx.x] = sm[0] + sm[1] + sm[2] + sm[3];
}

// single-block exclusive prefix scan of counts -> offsets (and fill cursors)
__global__ void scan_kernel(const float* __restrict__ counts,
                            int* __restrict__ offs, int* __restrict__ curs) {
    __shared__ int ps[1024];
    const int t = threadIdx.x;
    const int base = t * 8;
    int loc[8]; int s = 0;
    #pragma unroll
    for (int i = 0; i < 8; i++) { int c = (int)(counts[base + i] + 0.5f); loc[i] = s; s += c; }
    ps[t] = s;
    __syncthreads();
    for (int off = 1; off < 1024; off <<= 1) {
        int v = ps[t];
        int add = (t >= off) ? ps[t - off] : 0;
        __syncthreads();
        ps[t] = v + add;
        __syncthreads();
    }
    int excl = (t == 0) ? 0 : ps[t - 1];
    #pragma unroll
    for (int i = 0; i < 8; i++) {
        int o = excl + loc[i];
        offs[base + i] = o;
        curs[base + i] = o;
    }
    if (t == 1023) offs[KCODE] = ps[1023];
}

// bucket tokens by code (16K scattered atomics total)
__global__ void fill_kernel(const int* __restrict__ ws_idx,
                            int* __restrict__ curs, int* __restrict__ toklist) {
    int t = blockIdx.x * blockDim.x + threadIdx.x;
    if (t >= N_TOK) return;
    int k = ws_idx[t];
    int slot = atomicAdd(curs + k, 1);
    toklist[slot] = t;
}

__global__ void cluster_kernel(const float* __restrict__ ema_cs, const float* __restrict__ counts,
                               float* __restrict__ out_ncs, float* __restrict__ n_acc,
                               const float* __restrict__ psum, float* __restrict__ out_loss) {
    int i = blockIdx.x * blockDim.x + threadIdx.x;
    float v = 0.f;
    if (i < KCODE) {
        v = EMA * ema_cs[i] + (1.f - EMA) * counts[i];
        out_ncs[i] = v;
    }
    __shared__ float sm[4];
    __shared__ float sm2[4];
    int lane = threadIdx.x & 63, w = threadIdx.x >> 6;
    #pragma unroll
    for (int off = 32; off > 0; off >>= 1) v += __shfl_down(v, off, 64);
    if (lane == 0) sm[w] = v;
    __syncthreads();
    if (threadIdx.x == 0) atomicAdd(n_acc, sm[0] + sm[1] + sm[2] + sm[3]);
    if (blockIdx.x == 0) {
        float s = 0.f;
        for (int j = threadIdx.x; j < 4096; j += 256) s += psum[j];
        #pragma unroll
        for (int off = 32; off > 0; off >>= 1) s += __shfl_down(s, off, 64);
        if (lane == 0) sm2[w] = s;
        __syncthreads();
        if (threadIdx.x == 0)
            out_loss[0] = 1.25f * (sm2[0] + sm2[1] + sm2[2] + sm2[3]) / (float)(N_TOK * DDIM);
    }
}

// fused per-code embed-sum + EMA + codebook update: one wave per code.
__global__ void codebook_fused_kernel(const float* __restrict__ z,
                                      const int* __restrict__ offs, const int* __restrict__ toklist,
                                      const float* __restrict__ ema_es,
                                      const float* __restrict__ ncs, const float* __restrict__ n_acc,
                                      float* __restrict__ out_es, float* __restrict__ out_cb) {
    int k = (blockIdx.x * blockDim.x + threadIdx.x) >> 6;
    int lane = threadIdx.x & 63;
    if (k >= KCODE) return;
    int o0 = offs[k], o1 = offs[k + 1];
    float sum[6] = {0.f, 0.f, 0.f, 0.f, 0.f, 0.f};
    for (int s = o0; s < o1; s++) {
        int tok = toklist[s];
        const float* zr = z + (size_t)tok * DDIM;
        #pragma unroll
        for (int r = 0; r < 6; r++) sum[r] += zr[lane + 64 * r];
    }
    float n = n_acc[0];
    float smooth = (ncs[k] + EPS_F) / (n + (float)KCODE * EPS_F) * n;
    float inv = 1.f / smooth;
    const float* er = ema_es + (size_t)k * DDIM;
    float* oes = out_es + (size_t)k * DDIM;
    float* ocb = out_cb + (size_t)k * DDIM;
    #pragma unroll
    for (int r = 0; r < 6; r++) {
        int d = lane + 64 * r;
        float es = EMA * er[d] + (1.f - EMA) * sum[r];
        oes[d] = es;
        ocb[d] = es * inv;
    }
}

extern "C" void kernel_launch(void* const* d_in, const int* in_sizes, int n_in,
                              void* d_out, int out_size, void* d_ws, size_t ws_size,
                              hipStream_t stream) {
    const float* z       = (const float*)d_in[0];
    const float* cb      = (const float*)d_in[1];
    const float* ema_cs  = (const float*)d_in[2];
    const float* ema_es  = (const float*)d_in[3];

    float* out      = (float*)d_out;
    float* out_q    = out;
    float* out_idx  = out + 6291456;
    float* out_loss = out + 6307840;
    float* out_ncs  = out + 6307841;
    float* out_es   = out + 6316033;
    float* out_cb   = out + 9461761;

    char* w = (char*)d_ws;
    float* pd1    = (float*)(w + OFF_PD1);
    int*   pi1    = (int*)  (w + OFF_PI1);
    float* pd2    = (float*)(w + OFF_PD2);
    _Float16* cbh = (_Float16*)(w + OFF_CBH);
    int*   toklist= (int*)  (w + OFF_TOKL);
    int*   offs   = (int*)  (w + OFF_OFFS);
    int*   curs   = (int*)  (w + OFF_CURS);
    float* cnorm  = (float*)(w + OFF_CNORM);
    int*   flist  = (int*)  (w + OFF_FLIST);
    int*   fcnt   = (int*)  (w + OFF_FCNT);
    int*   ws_idx = (int*)  (w + OFF_WSIDX);
    float* counts = (float*)(w + OFF_COUNTS);
    float* psum   = (float*)(w + OFF_PSUM);
    float* n_acc  = (float*)(w + OFF_NACC);
    float* fd1    = (float*)(w + OFF_FD1);

    // zh scratch lives in out_q's first 12.58 MB (out_q fully rewritten later)
    _Float16* zh = (_Float16*)out;

    hipMemsetAsync(w + OFF_FCNT, 0, 256, stream);
    hipMemsetAsync(w + OFF_COUNTS, 0, 32768 + 256, stream);  // counts + sumsq + n_acc

    cnorm_kernel<<<KCODE * 64 / 256, 256, 0, stream>>>(cb, cnorm);

    // (N_TOK + KCODE) * DDIM / 8 elems-per-thread / 256 threads = 4608 blocks
    convert_kernel<<<4608, 256, 0, stream>>>(z, cb, zh, cbh);

    dim3 grid_am(N_TOK / 128, KCODE / 256, 1);
    argmin16_kernel<<<grid_am, 512, 0, stream>>>(zh, cbh, cnorm, pd1, pi1, pd2);

    topmerge_kernel<<<N_TOK / 256, 256, 0, stream>>>(pd1, pi1, pd2, ws_idx, out_idx, fcnt, flist, fd1);

    // band-limited exact rescore (reads pd1 for the band test; writes ws_idx/out_idx directly)
    rescore2_kernel<<<2048, 256, 0, stream>>>(z, cb, cnorm, pd1, fd1, flist, fcnt, ws_idx, out_idx);

    // segmented EMA path (pd* dead from here; region A reused for toklist/offs/curs)
    quantize_kernel<<<N_TOK * 64 / 256, 256, 0, stream>>>(z, cb, ws_idx, out_q, counts, psum);
    scan_kernel<<<1, 1024, 0, stream>>>(counts, offs, curs);
    fill_kernel<<<N_TOK / 256, 256, 0, stream>>>(ws_idx, curs, toklist);
    cluster_kernel<<<(KCODE + 255) / 256, 256, 0, stream>>>(ema_cs, counts, out_ncs, n_acc, psum, out_loss);
    codebook_fused_kernel<<<KCODE * 64 / 256, 256, 0, stream>>>(z, offs, toklist, ema_es, out_ncs, n_acc, out_es, out_cb);
}

// Round 10
// 587.265 us; speedup vs baseline: 1.1772x; 1.1772x over previous
//
#include <hip/hip_runtime.h>
#include <math.h>

#define N_TOK 16384
#define DDIM  384
#define KCODE 8192
#define EMA   0.99f
#define EPS_F 1e-5f
#define MARGIN 0.5f
#define NB 32            // KCODE / 256 code-blocks in coarse pass

typedef _Float16 f16x8 __attribute__((ext_vector_type(8)));
typedef float    f32x4 __attribute__((ext_vector_type(4)));

// ---- ws byte offsets (total <= proven 13,041,672 B) ----
#define OFF_PD1    0UL        // [NB][N_TOK] f32 coarse best dist
#define OFF_PI1    2097152UL  // [NB][N_TOK] i32 coarse best idx
#define OFF_PD2    4194304UL  // [NB][N_TOK] f32 coarse 2nd dist
#define OFF_CBH    6291456UL  // [KCODE*DDIM] f16 pre-converted codebook
#define OFF_TOKL   0UL        // phase3: [N_TOK] i32 tokens bucketed by code
#define OFF_OFFS   65536UL    // phase3: [KCODE+1] i32 segment offsets
#define OFF_CURS   98560UL    // phase3: [KCODE] i32 fill cursors
// outside region A:
#define OFF_WSIDX  12582912UL // [N_TOK] i32
#define OFF_COUNTS 12648448UL // [KCODE] f32
#define OFF_SUMSQ  12681216UL // f32 (unused, in zeroed range)
#define OFF_NACC   12681220UL // f32 (+pad to 12681472)
#define OFF_CNORM  12681472UL // [KCODE] f32
#define OFF_FLIST  12714240UL // [N_TOK] i32 flagged tokens
#define OFF_FCNT   12779776UL // i32 + pad to 12780032
#define OFF_PSUM   12780032UL // [4096] f32 per-block commitment partials -> 12796416
#define OFF_FD1    12796416UL // [N_TOK] f32 global f16-best dist per token -> 12861952

// async global->LDS, 16B per lane; dest = wave-uniform base + lane*16
typedef __attribute__((address_space(1))) const unsigned int gas_uint;
typedef __attribute__((address_space(3))) unsigned int       las_uint;
__device__ __forceinline__ void gload_lds16(const void* g, void* l) {
    __builtin_amdgcn_global_load_lds((gas_uint*)g, (las_uint*)l, 16, 0, 0);
}

__global__ void cnorm_kernel(const float* __restrict__ cb, float* __restrict__ cnorm) {
    int wave = (blockIdx.x * blockDim.x + threadIdx.x) >> 6;
    int lane = threadIdx.x & 63;
    if (wave >= KCODE) return;
    const float* row = cb + (size_t)wave * DDIM;
    float s = 0.f;
    #pragma unroll
    for (int r = 0; r < 6; r++) { float v = row[lane + 64 * r]; s += v * v; }
    #pragma unroll
    for (int off = 32; off > 0; off >>= 1) s += __shfl_down(s, off, 64);
    if (lane == 0) cnorm[wave] = s;
}

// one-shot fp32 -> f16 conversion of z (into out_q scratch) and cb (into ws).
__global__ void convert_kernel(const float* __restrict__ z, const float* __restrict__ cb,
                               _Float16* __restrict__ zh, _Float16* __restrict__ cbh) {
    size_t e = ((size_t)blockIdx.x * blockDim.x + threadIdx.x) * 8;
    const size_t NZ = (size_t)N_TOK * DDIM;
    const float* s;
    _Float16* d;
    if (e < NZ) { s = z + e; d = zh + e; }
    else        { s = cb + (e - NZ); d = cbh + (e - NZ); }
    float4 v0 = *(const float4*)(s);
    float4 v1 = *(const float4*)(s + 4);
    f16x8 h;
    h[0]=(_Float16)v0.x; h[1]=(_Float16)v0.y; h[2]=(_Float16)v0.z; h[3]=(_Float16)v0.w;
    h[4]=(_Float16)v1.x; h[5]=(_Float16)v1.y; h[6]=(_Float16)v1.z; h[7]=(_Float16)v1.w;
    *(f16x8*)d = h;
}

// ---- coarse pass: f16 MFMA GEMM (z . c^T), per-token top-2 over 256-code blocks ----
// tile 128x256, BK=32, 8 waves, SINGLE buffer (24.6KB -> 2 blocks/CU, the proven
// occupancy point; 2x49152 dbuf broke the ~64KB schedulable pool, round 9).
// Latency fix at constant LDS: issue next tile's global_load_lds BETWEEN the
// read-done barrier and the MFMA cluster -> loads have the whole MFMA phase
// (~1200 cyc) in flight before the next data-ready vmcnt(0) drain, instead of
// draining cold right after issue (round-8 structure).
//   barrier(ready) -> ds_read -> barrier(read-done) -> gload next -> 16 MFMA
// Swizzle (round-4-verified): rows 64B = 4x16B chunks, slot = chunk ^ ((row>>1)&3);
// linear LDS dest + pre-permuted global source + XOR'd fragment reads.
// Epilogue xd/xi scratch ALIASES As (dead after the K loop).
__launch_bounds__(512)
__global__ void argmin16_kernel(const _Float16* __restrict__ zh, const _Float16* __restrict__ cbh,
                                const float* __restrict__ cnorm,
                                float* __restrict__ pd1, int* __restrict__ pi1,
                                float* __restrict__ pd2) {
    __shared__ _Float16 As[128 * 32];   // 8 KB (epilogue aliases this)
    __shared__ _Float16 Bs[256 * 32];   // 16 KB

    const int tid  = threadIdx.x;
    const int lane = tid & 63;
    const int wv   = tid >> 6;
    const int wy   = wv >> 2;
    const int wx   = wv & 3;
    const int m0   = blockIdx.x * 128;
    const int n0   = blockIdx.y * 256;
    const int l15  = lane & 15;
    const int l4   = lane >> 4;
    const int csw  = (l15 >> 1) & 3;    // (row>>1)&3 seen by fragment reads

    f32x4 acc[4][4];
    #pragma unroll
    for (int i = 0; i < 4; i++)
        #pragma unroll
        for (int j = 0; j < 4; j++) acc[i][j] = (f32x4){0.f, 0.f, 0.f, 0.f};

    // staging: thread q writes LDS byte q*16 -> row q>>2, slot-chunk q&3.
    // source chunk j = (q&3) ^ ((q>>3)&3)   (row = q>>2)
    const int arow = tid >> 2;
    const int jch  = (tid & 3) ^ ((tid >> 3) & 3);
    const _Float16* a_src  = zh  + (size_t)(m0 + arow) * DDIM + jch * 8;
    const _Float16* b_src0 = cbh + (size_t)(n0 + arow) * DDIM + jch * 8;          // q = tid
    const _Float16* b_src1 = cbh + (size_t)(n0 + 128 + arow) * DDIM + jch * 8;    // q = tid+512
    const int dofs = wv * 512;     // wave-uniform LDS element base

    // prologue: stage tile 0
    gload_lds16(a_src,  As + dofs);
    gload_lds16(b_src0, Bs + dofs);
    gload_lds16(b_src1, Bs + dofs + 4096);

    for (int it = 0; it < 12; it++) {
        __syncthreads();   // data-ready: vmcnt(0) drain (covered by prior MFMA phase)
        f16x8 af[4], bf[4];
        #pragma unroll
        for (int im = 0; im < 4; im++)
            af[im] = *(const f16x8*)(As + (wy * 64 + im * 16 + l15) * 32 + (l4 ^ csw) * 8);
        #pragma unroll
        for (int in = 0; in < 4; in++)
            bf[in] = *(const f16x8*)(Bs + (wx * 64 + in * 16 + l15) * 32 + (l4 ^ csw) * 8);
        __syncthreads();   // read-done: lgkm drained, buffer free for overwrite
        if (it < 11) {
            int kc = (it + 1) * 32;
            gload_lds16(a_src + kc,  As + dofs);
            gload_lds16(b_src0 + kc, Bs + dofs);
            gload_lds16(b_src1 + kc, Bs + dofs + 4096);
        }
        #pragma unroll
        for (int im = 0; im < 4; im++)
            #pragma unroll
            for (int in = 0; in < 4; in++)
                acc[im][in] = __builtin_amdgcn_mfma_f32_16x16x32_f16(af[im], bf[in], acc[im][in], 0, 0, 0);
    }

    // epilogue scratch aliases As (no LDS reads of As/Bs after the loop's last
    // read-done barrier, which all waves have passed)
    float* xd1 = (float*)&As[0];             // 512 f32 = 2KB
    float* xd2 = xd1 + 512;                  // 2KB
    int*   xi1 = (int*)(xd1 + 1024);         // 2KB

    // dist = ||c||^2 - 2 z.c ; per-token top-2. C/D: col=lane&15, row=(lane>>4)*4+reg
    float cn[4]; int cid[4];
    #pragma unroll
    for (int in = 0; in < 4; in++) {
        cid[in] = n0 + wx * 64 + in * 16 + l15;
        cn[in] = cnorm[cid[in]];
    }
    #pragma unroll
    for (int im = 0; im < 4; im++) {
        #pragma unroll
        for (int reg = 0; reg < 4; reg++) {
            float d1 = cn[0] - 2.f * acc[im][0][reg];
            int   i1 = cid[0];
            float d2 = 3.4e38f;
            #pragma unroll
            for (int in = 1; in < 4; in++) {
                float dd = cn[in] - 2.f * acc[im][in][reg];
                if (dd < d1) { d2 = d1; d1 = dd; i1 = cid[in]; }
                else d2 = fminf(d2, dd);
            }
            #pragma unroll
            for (int off = 1; off < 16; off <<= 1) {
                float od1 = __shfl_xor(d1, off, 16);
                int   oi1 = __shfl_xor(i1, off, 16);
                float od2 = __shfl_xor(d2, off, 16);
                if (od1 < d1 || (od1 == d1 && oi1 < i1)) { d2 = fminf(d1, od2); d1 = od1; i1 = oi1; }
                else d2 = fminf(d2, od1);
            }
            if (l15 == 0) {
                int tl = wy * 64 + im * 16 + l4 * 4 + reg;
                xd1[tl * 4 + wx] = d1; xi1[tl * 4 + wx] = i1; xd2[tl * 4 + wx] = d2;
            }
        }
    }
    __syncthreads();
    if (tid < 128) {
        float d1 = xd1[tid * 4], d2 = xd2[tid * 4];
        int   i1 = xi1[tid * 4];
        #pragma unroll
        for (int x = 1; x < 4; x++) {
            float od1 = xd1[tid * 4 + x], od2 = xd2[tid * 4 + x];
            int   oi1 = xi1[tid * 4 + x];
            if (od1 < d1 || (od1 == d1 && oi1 < i1)) { d2 = fminf(d1, od2); d1 = od1; i1 = oi1; }
            else d2 = fminf(d2, od1);
        }
        size_t o = (size_t)blockIdx.y * N_TOK + m0 + tid;
        pd1[o] = d1; pi1[o] = i1; pd2[o] = d2;
    }
}

// merge 32 coarse partials per token; flag near-ties; record global f16-best dist
__global__ void topmerge_kernel(const float* __restrict__ pd1, const int* __restrict__ pi1,
                                const float* __restrict__ pd2,
                                int* __restrict__ ws_idx, float* __restrict__ out_idx,
                                int* __restrict__ fcnt, int* __restrict__ flist,
                                float* __restrict__ fd1) {
    int t = blockIdx.x * blockDim.x + threadIdx.x;
    if (t >= N_TOK) return;
    float d1 = pd1[t], d2 = pd2[t];
    int   i1 = pi1[t];
    for (int nb = 1; nb < NB; nb++) {
        size_t o = (size_t)nb * N_TOK + t;
        float od1 = pd1[o], od2 = pd2[o];
        int   oi1 = pi1[o];
        if (od1 < d1 || (od1 == d1 && oi1 < i1)) { d2 = fminf(d1, od2); d1 = od1; i1 = oi1; }
        else d2 = fminf(d2, od1);
    }
    ws_idx[t] = i1;
    out_idx[t] = (float)i1;
    fd1[t] = d1;
    if (d2 - d1 < MARGIN) {
        int s = atomicAdd(fcnt, 1);
        flist[s] = t;
    }
}

// band-limited exact rescore: one WAVE per flagged token; only code-blocks whose
// coarse minimum lies within [d1, d1+MARGIN] can contain the exact argmin.
__launch_bounds__(256)
__global__ void rescore2_kernel(const float* __restrict__ z, const float* __restrict__ cb,
                                const float* __restrict__ cnorm,
                                const float* __restrict__ pd1, const float* __restrict__ fd1,
                                const int* __restrict__ flist, const int* __restrict__ fcnt,
                                int* __restrict__ ws_idx, float* __restrict__ out_idx) {
    __shared__ float zt[4 * 384];       // per-wave private z row (no cross-wave sync!)
    const int lane = threadIdx.x & 63;
    const int wv   = threadIdx.x >> 6;
    const int count = fcnt[0];
    float* zrow = zt + wv * 384;
    for (int slot = blockIdx.x * 4 + wv; slot < count; slot += 2048 * 4) {
        int t = flist[slot];
        const float* zr = z + (size_t)t * DDIM;
        #pragma unroll
        for (int r = 0; r < 6; r++) zrow[lane + 64 * r] = zr[lane + 64 * r];
        float band = fd1[t] + MARGIN;
        float bd = 3.4e38f; int bi = 0x7fffffff;
        for (int nb = 0; nb < NB; nb++) {
            if (pd1[(size_t)nb * N_TOK + t] >= band) continue;
            #pragma unroll
            for (int c4 = 0; c4 < 4; c4++) {
                int c = nb * 256 + c4 * 64 + lane;
                const float* cr = cb + (size_t)c * DDIM;
                float a = 0.f;
                for (int d4 = 0; d4 < 96; d4++) {
                    float4 cv = *(const float4*)(cr + d4 * 4);
                    float4 zv = *(const float4*)(zrow + d4 * 4);   // LDS broadcast
                    a = fmaf(zv.x, cv.x, a);
                    a = fmaf(zv.y, cv.y, a);
                    a = fmaf(zv.z, cv.z, a);
                    a = fmaf(zv.w, cv.w, a);
                }
                float dd = cnorm[c] - 2.f * a;
                if (dd < bd) { bd = dd; bi = c; }
            }
        }
        #pragma unroll
        for (int off = 32; off > 0; off >>= 1) {
            float od = __shfl_xor(bd, off, 64);
            int   oi = __shfl_xor(bi, off, 64);
            if (od < bd || (od == bd && oi < bi)) { bd = od; bi = oi; }
        }
        if (lane == 0) { ws_idx[t] = bi; out_idx[t] = (float)bi; }
    }
}

// per-token: gather quantized row, commitment partial (per-BLOCK), counts.
__global__ void quantize_kernel(const float* __restrict__ z, const float* __restrict__ cb,
                                const int* __restrict__ ws_idx,
                                float* __restrict__ out_q,
                                float* __restrict__ counts, float* __restrict__ psum) {
    __shared__ float sm[4];
    int t = (blockIdx.x * blockDim.x + threadIdx.x) >> 6;
    int lane = threadIdx.x & 63, wv = threadIdx.x >> 6;
    int k = ws_idx[t];
    const float* zr = z + (size_t)t * DDIM;
    const float* cr = cb + (size_t)k * DDIM;
    float* qr = out_q + (size_t)t * DDIM;
    float s = 0.f;
    #pragma unroll
    for (int r = 0; r < 6; r++) {
        int d = lane + 64 * r;
        float zv = zr[d];
        float qv = cr[d];
        qr[d] = qv;
        float df = zv - qv;
        s += df * df;
    }
    #pragma unroll
    for (int off = 32; off > 0; off >>= 1) s += __shfl_down(s, off, 64);
    if (lane == 0) {
        sm[wv] = s;
        atomicAdd(counts + k, 1.0f);
    }
    __syncthreads();
    if (threadIdx.x == 0) psum[blockIdx.x] = sm[0] + sm[1] + sm[2] + sm[3];
}

// single-block exclusive prefix scan of counts -> offsets (and fill cursors)
__global__ void scan_kernel(const float* __restrict__ counts,
                            int* __restrict__ offs, int* __restrict__ curs) {
    __shared__ int ps[1024];
    const int t = threadIdx.x;
    const int base = t * 8;
    int loc[8]; int s = 0;
    #pragma unroll
    for (int i = 0; i < 8; i++) { int c = (int)(counts[base + i] + 0.5f); loc[i] = s; s += c; }
    ps[t] = s;
    __syncthreads();
    for (int off = 1; off < 1024; off <<= 1) {
        int v = ps[t];
        int add = (t >= off) ? ps[t - off] : 0;
        __syncthreads();
        ps[t] = v + add;
        __syncthreads();
    }
    int excl = (t == 0) ? 0 : ps[t - 1];
    #pragma unroll
    for (int i = 0; i < 8; i++) {
        int o = excl + loc[i];
        offs[base + i] = o;
        curs[base + i] = o;
    }
    if (t == 1023) offs[KCODE] = ps[1023];
}

// bucket tokens by code (16K scattered atomics total)
__global__ void fill_kernel(const int* __restrict__ ws_idx,
                            int* __restrict__ curs, int* __restrict__ toklist) {
    int t = blockIdx.x * blockDim.x + threadIdx.x;
    if (t >= N_TOK) return;
    int k = ws_idx[t];
    int slot = atomicAdd(curs + k, 1);
    toklist[slot] = t;
}

__global__ void cluster_kernel(const float* __restrict__ ema_cs, const float* __restrict__ counts,
                               float* __restrict__ out_ncs, float* __restrict__ n_acc,
                               const float* __restrict__ psum, float* __restrict__ out_loss) {
    int i = blockIdx.x * blockDim.x + threadIdx.x;
    float v = 0.f;
    if (i < KCODE) {
        v = EMA * ema_cs[i] + (1.f - EMA) * counts[i];
        out_ncs[i] = v;
    }
    __shared__ float sm[4];
    __shared__ float sm2[4];
    int lane = threadIdx.x & 63, w = threadIdx.x >> 6;
    #pragma unroll
    for (int off = 32; off > 0; off >>= 1) v += __shfl_down(v, off, 64);
    if (lane == 0) sm[w] = v;
    __syncthreads();
    if (threadIdx.x == 0) atomicAdd(n_acc, sm[0] + sm[1] + sm[2] + sm[3]);
    if (blockIdx.x == 0) {
        float s = 0.f;
        for (int j = threadIdx.x; j < 4096; j += 256) s += psum[j];
        #pragma unroll
        for (int off = 32; off > 0; off >>= 1) s += __shfl_down(s, off, 64);
        if (lane == 0) sm2[w] = s;
        __syncthreads();
        if (threadIdx.x == 0)
            out_loss[0] = 1.25f * (sm2[0] + sm2[1] + sm2[2] + sm2[3]) / (float)(N_TOK * DDIM);
    }
}

// fused per-code embed-sum + EMA + codebook update: one wave per code.
__global__ void codebook_fused_kernel(const float* __restrict__ z,
                                      const int* __restrict__ offs, const int* __restrict__ toklist,
                                      const float* __restrict__ ema_es,
                                      const float* __restrict__ ncs, const float* __restrict__ n_acc,
                                      float* __restrict__ out_es, float* __restrict__ out_cb) {
    int k = (blockIdx.x * blockDim.x + threadIdx.x) >> 6;
    int lane = threadIdx.x & 63;
    if (k >= KCODE) return;
    int o0 = offs[k], o1 = offs[k + 1];
    float sum[6] = {0.f, 0.f, 0.f, 0.f, 0.f, 0.f};
    for (int s = o0; s < o1; s++) {
        int tok = toklist[s];
        const float* zr = z + (size_t)tok * DDIM;
        #pragma unroll
        for (int r = 0; r < 6; r++) sum[r] += zr[lane + 64 * r];
    }
    float n = n_acc[0];
    float smooth = (ncs[k] + EPS_F) / (n + (float)KCODE * EPS_F) * n;
    float inv = 1.f / smooth;
    const float* er = ema_es + (size_t)k * DDIM;
    float* oes = out_es + (size_t)k * DDIM;
    float* ocb = out_cb + (size_t)k * DDIM;
    #pragma unroll
    for (int r = 0; r < 6; r++) {
        int d = lane + 64 * r;
        float es = EMA * er[d] + (1.f - EMA) * sum[r];
        oes[d] = es;
        ocb[d] = es * inv;
    }
}

extern "C" void kernel_launch(void* const* d_in, const int* in_sizes, int n_in,
                              void* d_out, int out_size, void* d_ws, size_t ws_size,
                              hipStream_t stream) {
    const float* z       = (const float*)d_in[0];
    const float* cb      = (const float*)d_in[1];
    const float* ema_cs  = (const float*)d_in[2];
    const float* ema_es  = (const float*)d_in[3];

    float* out      = (float*)d_out;
    float* out_q    = out;
    float* out_idx  = out + 6291456;
    float* out_loss = out + 6307840;
    float* out_ncs  = out + 6307841;
    float* out_es   = out + 6316033;
    float* out_cb   = out + 9461761;

    char* w = (char*)d_ws;
    float* pd1    = (float*)(w + OFF_PD1);
    int*   pi1    = (int*)  (w + OFF_PI1);
    float* pd2    = (float*)(w + OFF_PD2);
    _Float16* cbh = (_Float16*)(w + OFF_CBH);
    int*   toklist= (int*)  (w + OFF_TOKL);
    int*   offs   = (int*)  (w + OFF_OFFS);
    int*   curs   = (int*)  (w + OFF_CURS);
    float* cnorm  = (float*)(w + OFF_CNORM);
    int*   flist  = (int*)  (w + OFF_FLIST);
    int*   fcnt   = (int*)  (w + OFF_FCNT);
    int*   ws_idx = (int*)  (w + OFF_WSIDX);
    float* counts = (float*)(w + OFF_COUNTS);
    float* psum   = (float*)(w + OFF_PSUM);
    float* n_acc  = (float*)(w + OFF_NACC);
    float* fd1    = (float*)(w + OFF_FD1);

    // zh scratch lives in out_q's first 12.58 MB (out_q fully rewritten later)
    _Float16* zh = (_Float16*)out;

    hipMemsetAsync(w + OFF_FCNT, 0, 256, stream);
    hipMemsetAsync(w + OFF_COUNTS, 0, 32768 + 256, stream);  // counts + sumsq + n_acc

    cnorm_kernel<<<KCODE * 64 / 256, 256, 0, stream>>>(cb, cnorm);

    // (N_TOK + KCODE) * DDIM / 8 elems-per-thread / 256 threads = 4608 blocks
    convert_kernel<<<4608, 256, 0, stream>>>(z, cb, zh, cbh);

    dim3 grid_am(N_TOK / 128, KCODE / 256, 1);
    argmin16_kernel<<<grid_am, 512, 0, stream>>>(zh, cbh, cnorm, pd1, pi1, pd2);

    topmerge_kernel<<<N_TOK / 256, 256, 0, stream>>>(pd1, pi1, pd2, ws_idx, out_idx, fcnt, flist, fd1);

    // band-limited exact rescore (reads pd1 for the band test; writes ws_idx/out_idx directly)
    rescore2_kernel<<<2048, 256, 0, stream>>>(z, cb, cnorm, pd1, fd1, flist, fcnt, ws_idx, out_idx);

    // segmented EMA path (pd* dead from here; region A reused for toklist/offs/curs)
    quantize_kernel<<<N_TOK * 64 / 256, 256, 0, stream>>>(z, cb, ws_idx, out_q, counts, psum);
    scan_kernel<<<1, 1024, 0, stream>>>(counts, offs, curs);
    fill_kernel<<<N_TOK / 256, 256, 0, stream>>>(ws_idx, curs, toklist);
    cluster_kernel<<<(KCODE + 255) / 256, 256, 0, stream>>>(ema_cs, counts, out_ncs, n_acc, psum, out_loss);
    codebook_fused_kernel<<<KCODE * 64 / 256, 256, 0, stream>>>(z, offs, toklist, ema_es, out_ncs, n_acc, out_es, out_cb);
}

// Round 11
// 572.026 us; speedup vs baseline: 1.2086x; 1.0266x over previous
//
#include <hip/hip_runtime.h>
#include <math.h>

#define N_TOK 16384
#define DDIM  384
#define KCODE 8192
#define EMA   0.99f
#define EPS_F 1e-5f
#define MARGIN 0.5f
#define NB 32            // KCODE / 256 code-blocks in coarse pass

typedef _Float16 f16x8 __attribute__((ext_vector_type(8)));
typedef float    f32x4 __attribute__((ext_vector_type(4)));

// ---- ws byte offsets (total <= proven 13,041,672 B) ----
#define OFF_PD1    0UL        // [NB][N_TOK] f32 coarse best dist
#define OFF_PI1    2097152UL  // [NB][N_TOK] i32 coarse best idx
#define OFF_PD2    4194304UL  // [NB][N_TOK] f32 coarse 2nd dist
#define OFF_CBH    6291456UL  // [KCODE*DDIM] f16 pre-converted codebook
#define OFF_TOKL   0UL        // phase3: [N_TOK] i32 tokens bucketed by code
#define OFF_OFFS   65536UL    // phase3: [KCODE+1] i32 segment offsets
#define OFF_CURS   98560UL    // phase3: [KCODE] i32 fill cursors
// outside region A:
#define OFF_WSIDX  12582912UL // [N_TOK] i32
#define OFF_COUNTS 12648448UL // [KCODE] f32
#define OFF_SUMSQ  12681216UL // f32 (unused, in zeroed range)
#define OFF_NACC   12681220UL // f32 (+pad to 12681472)
#define OFF_CNORM  12681472UL // [KCODE] f32
#define OFF_FLIST  12714240UL // [N_TOK] i32 flagged tokens
#define OFF_FCNT   12779776UL // i32 + pad to 12780032
#define OFF_PSUM   12780032UL // [4096] f32 per-block commitment partials -> 12796416
#define OFF_FD1    12796416UL // [N_TOK] f32 global f16-best dist per token -> 12861952

// async global->LDS, 16B per lane; dest = wave-uniform base + lane*16
typedef __attribute__((address_space(1))) const unsigned int gas_uint;
typedef __attribute__((address_space(3))) unsigned int       las_uint;
__device__ __forceinline__ void gload_lds16(const void* g, void* l) {
    __builtin_amdgcn_global_load_lds((gas_uint*)g, (las_uint*)l, 16, 0, 0);
}

// row-wise fused fp32->f16 convert (z and cb) + codebook row norms (one wave/row).
// float2 per lane per step: 512B/wave coalesced loads, 256B f16 stores.
__global__ void convert_norm_kernel(const float* __restrict__ z, const float* __restrict__ cb,
                                    _Float16* __restrict__ zh, _Float16* __restrict__ cbh,
                                    float* __restrict__ cnorm) {
    int row  = (blockIdx.x * blockDim.x + threadIdx.x) >> 6;
    int lane = threadIdx.x & 63;
    const float* src;
    _Float16* dst;
    bool is_cb = (row >= N_TOK);
    if (is_cb) { int k = row - N_TOK; src = cb + (size_t)k * DDIM; dst = cbh + (size_t)k * DDIM; }
    else       {                      src = z  + (size_t)row * DDIM; dst = zh + (size_t)row * DDIM; }
    float s = 0.f;
    #pragma unroll
    for (int r = 0; r < 3; r++) {
        int e = (lane + 64 * r) * 2;
        float2 v = *(const float2*)(src + e);
        s = fmaf(v.x, v.x, fmaf(v.y, v.y, s));
        _Float16 h0 = (_Float16)v.x, h1 = (_Float16)v.y;
        dst[e] = h0; dst[e + 1] = h1;
    }
    if (is_cb) {
        #pragma unroll
        for (int off = 32; off > 0; off >>= 1) s += __shfl_down(s, off, 64);
        if (lane == 0) cnorm[row - N_TOK] = s;
    }
}

// ---- coarse pass: f16 MFMA GEMM (z . c^T), per-token top-2 over 256-code blocks ----
// tile 128x256, BK=64 (6 iters, 32 MFMA between barrier pairs - half the drains of
// BK=32), 8 waves, single buffer 48KB. Occupancy limiter is the unified VGPR+AGPR
// file (rounds 2/9/10 triangulated: 120 regs -> 2 blocks, 132+ -> 1 block). Keep
// fragment set REUSED across the two k-substeps (8 frags = 32 VGPR live) and pin
// with __launch_bounds__(512,4) -> <=128 regs -> 2 blocks/CU.
// Swizzle (round-2 verified): rows 128B = 8x16B chunks; LDS[r][slot s] = src[r][s^(r&7)];
// linear gload dest + pre-permuted source chunk; reads use slot (ks*4+l4)^(l15&7).
// Epilogue xd/xi scratch aliases As.
__launch_bounds__(512, 4)
__global__ void argmin16_kernel(const _Float16* __restrict__ zh, const _Float16* __restrict__ cbh,
                                const float* __restrict__ cnorm,
                                float* __restrict__ pd1, int* __restrict__ pi1,
                                float* __restrict__ pd2) {
    __shared__ _Float16 As[128 * 64];   // 16 KB (epilogue aliases this)
    __shared__ _Float16 Bs[256 * 64];   // 32 KB

    const int tid  = threadIdx.x;
    const int lane = tid & 63;
    const int wv   = tid >> 6;
    const int wy   = wv >> 2;
    const int wx   = wv & 3;
    const int m0   = blockIdx.x * 128;
    const int n0   = blockIdx.y * 256;
    const int l15  = lane & 15;
    const int l4   = lane >> 4;
    const int rsw  = l15 & 7;           // (row&7) seen by fragment reads

    f32x4 acc[4][4];
    #pragma unroll
    for (int i = 0; i < 4; i++)
        #pragma unroll
        for (int j = 0; j < 4; j++) acc[i][j] = (f32x4){0.f, 0.f, 0.f, 0.f};

    // staging: each gload covers 64 rows (8 rows/wave, 8 lanes/row, 16B each).
    // lane l -> row wv*8 + (l>>3); LDS chunk-slot l&7 holds source chunk (l&7)^(row&7)
    const int r8  = lane >> 3;
    const int jch = (lane & 7) ^ (r8 & 7);       // row&7 == r8&7 (wv*8 aligned)
    const _Float16* a_g = zh  + (size_t)(m0 + wv * 8 + r8) * DDIM + jch * 8;
    const _Float16* b_g = cbh + (size_t)(n0 + wv * 8 + r8) * DDIM + jch * 8;
    _Float16* a_d = As + wv * 512;               // 1024B per wave-instr
    _Float16* b_d = Bs + wv * 512;

    // prologue: stage tile 0
    gload_lds16(a_g,                      a_d);
    gload_lds16(a_g + (size_t)64 * DDIM,  a_d + 4096);
    gload_lds16(b_g,                      b_d);
    gload_lds16(b_g + (size_t)64 * DDIM,  b_d + 4096);
    gload_lds16(b_g + (size_t)128 * DDIM, b_d + 8192);
    gload_lds16(b_g + (size_t)192 * DDIM, b_d + 12288);

    for (int it = 0; it < 6; it++) {
        __syncthreads();   // data-ready (vmcnt drain of last iter's stage)
        f16x8 af[4], bf[4];
        // k-substep 0
        #pragma unroll
        for (int im = 0; im < 4; im++)
            af[im] = *(const f16x8*)(As + (wy * 64 + im * 16 + l15) * 64 + (l4 ^ rsw) * 8);
        #pragma unroll
        for (int in = 0; in < 4; in++)
            bf[in] = *(const f16x8*)(Bs + (wx * 64 + in * 16 + l15) * 64 + (l4 ^ rsw) * 8);
        #pragma unroll
        for (int im = 0; im < 4; im++)
            #pragma unroll
            for (int in = 0; in < 4; in++)
                acc[im][in] = __builtin_amdgcn_mfma_f32_16x16x32_f16(af[im], bf[in], acc[im][in], 0, 0, 0);
        // k-substep 1: reuse the same fragment registers (keeps VGPR+AGPR <= 128)
        #pragma unroll
        for (int im = 0; im < 4; im++)
            af[im] = *(const f16x8*)(As + (wy * 64 + im * 16 + l15) * 64 + ((4 + l4) ^ rsw) * 8);
        #pragma unroll
        for (int in = 0; in < 4; in++)
            bf[in] = *(const f16x8*)(Bs + (wx * 64 + in * 16 + l15) * 64 + ((4 + l4) ^ rsw) * 8);
        __syncthreads();   // read-done: buffer free for overwrite
        if (it < 5) {
            int kc = (it + 1) * 64;
            gload_lds16(a_g + kc,                      a_d);
            gload_lds16(a_g + (size_t)64 * DDIM + kc,  a_d + 4096);
            gload_lds16(b_g + kc,                      b_d);
            gload_lds16(b_g + (size_t)64 * DDIM + kc,  b_d + 4096);
            gload_lds16(b_g + (size_t)128 * DDIM + kc, b_d + 8192);
            gload_lds16(b_g + (size_t)192 * DDIM + kc, b_d + 12288);
        }
        #pragma unroll
        for (int im = 0; im < 4; im++)
            #pragma unroll
            for (int in = 0; in < 4; in++)
                acc[im][in] = __builtin_amdgcn_mfma_f32_16x16x32_f16(af[im], bf[in], acc[im][in], 0, 0, 0);
    }

    // epilogue scratch aliases As (all waves past the loop's final read-done barrier)
    float* xd1 = (float*)&As[0];             // 2KB
    float* xd2 = xd1 + 512;                  // 2KB
    int*   xi1 = (int*)(xd1 + 1024);         // 2KB

    // dist = ||c||^2 - 2 z.c ; per-token top-2. C/D: col=lane&15, row=(lane>>4)*4+reg
    float cn[4]; int cid[4];
    #pragma unroll
    for (int in = 0; in < 4; in++) {
        cid[in] = n0 + wx * 64 + in * 16 + l15;
        cn[in] = cnorm[cid[in]];
    }
    #pragma unroll
    for (int im = 0; im < 4; im++) {
        #pragma unroll
        for (int reg = 0; reg < 4; reg++) {
            float d1 = cn[0] - 2.f * acc[im][0][reg];
            int   i1 = cid[0];
            float d2 = 3.4e38f;
            #pragma unroll
            for (int in = 1; in < 4; in++) {
                float dd = cn[in] - 2.f * acc[im][in][reg];
                if (dd < d1) { d2 = d1; d1 = dd; i1 = cid[in]; }
                else d2 = fminf(d2, dd);
            }
            #pragma unroll
            for (int off = 1; off < 16; off <<= 1) {
                float od1 = __shfl_xor(d1, off, 16);
                int   oi1 = __shfl_xor(i1, off, 16);
                float od2 = __shfl_xor(d2, off, 16);
                if (od1 < d1 || (od1 == d1 && oi1 < i1)) { d2 = fminf(d1, od2); d1 = od1; i1 = oi1; }
                else d2 = fminf(d2, od1);
            }
            if (l15 == 0) {
                int tl = wy * 64 + im * 16 + l4 * 4 + reg;
                xd1[tl * 4 + wx] = d1; xi1[tl * 4 + wx] = i1; xd2[tl * 4 + wx] = d2;
            }
        }
    }
    __syncthreads();
    if (tid < 128) {
        float d1 = xd1[tid * 4], d2 = xd2[tid * 4];
        int   i1 = xi1[tid * 4];
        #pragma unroll
        for (int x = 1; x < 4; x++) {
            float od1 = xd1[tid * 4 + x], od2 = xd2[tid * 4 + x];
            int   oi1 = xi1[tid * 4 + x];
            if (od1 < d1 || (od1 == d1 && oi1 < i1)) { d2 = fminf(d1, od2); d1 = od1; i1 = oi1; }
            else d2 = fminf(d2, od1);
        }
        size_t o = (size_t)blockIdx.y * N_TOK + m0 + tid;
        pd1[o] = d1; pi1[o] = i1; pd2[o] = d2;
    }
}

// merge 32 coarse partials per token; flag near-ties; record global f16-best dist
__global__ void topmerge_kernel(const float* __restrict__ pd1, const int* __restrict__ pi1,
                                const float* __restrict__ pd2,
                                int* __restrict__ ws_idx, float* __restrict__ out_idx,
                                int* __restrict__ fcnt, int* __restrict__ flist,
                                float* __restrict__ fd1) {
    int t = blockIdx.x * blockDim.x + threadIdx.x;
    if (t >= N_TOK) return;
    float d1 = pd1[t], d2 = pd2[t];
    int   i1 = pi1[t];
    for (int nb = 1; nb < NB; nb++) {
        size_t o = (size_t)nb * N_TOK + t;
        float od1 = pd1[o], od2 = pd2[o];
        int   oi1 = pi1[o];
        if (od1 < d1 || (od1 == d1 && oi1 < i1)) { d2 = fminf(d1, od2); d1 = od1; i1 = oi1; }
        else d2 = fminf(d2, od1);
    }
    ws_idx[t] = i1;
    out_idx[t] = (float)i1;
    fd1[t] = d1;
    if (d2 - d1 < MARGIN) {
        int s = atomicAdd(fcnt, 1);
        flist[s] = t;
    }
}

// band-limited exact rescore: one WAVE per flagged token; only code-blocks whose
// coarse minimum lies within [d1, d1+MARGIN] can contain the exact argmin.
__launch_bounds__(256)
__global__ void rescore2_kernel(const float* __restrict__ z, const float* __restrict__ cb,
                                const float* __restrict__ cnorm,
                                const float* __restrict__ pd1, const float* __restrict__ fd1,
                                const int* __restrict__ flist, const int* __restrict__ fcnt,
                                int* __restrict__ ws_idx, float* __restrict__ out_idx) {
    __shared__ float zt[4 * 384];       // per-wave private z row (no cross-wave sync!)
    const int lane = threadIdx.x & 63;
    const int wv   = threadIdx.x >> 6;
    const int count = fcnt[0];
    float* zrow = zt + wv * 384;
    for (int slot = blockIdx.x * 4 + wv; slot < count; slot += 2048 * 4) {
        int t = flist[slot];
        const float* zr = z + (size_t)t * DDIM;
        #pragma unroll
        for (int r = 0; r < 6; r++) zrow[lane + 64 * r] = zr[lane + 64 * r];
        float band = fd1[t] + MARGIN;
        float bd = 3.4e38f; int bi = 0x7fffffff;
        for (int nb = 0; nb < NB; nb++) {
            if (pd1[(size_t)nb * N_TOK + t] >= band) continue;
            #pragma unroll
            for (int c4 = 0; c4 < 4; c4++) {
                int c = nb * 256 + c4 * 64 + lane;
                const float* cr = cb + (size_t)c * DDIM;
                float a = 0.f;
                for (int d4 = 0; d4 < 96; d4++) {
                    float4 cv = *(const float4*)(cr + d4 * 4);
                    float4 zv = *(const float4*)(zrow + d4 * 4);   // LDS broadcast
                    a = fmaf(zv.x, cv.x, a);
                    a = fmaf(zv.y, cv.y, a);
                    a = fmaf(zv.z, cv.z, a);
                    a = fmaf(zv.w, cv.w, a);
                }
                float dd = cnorm[c] - 2.f * a;
                if (dd < bd) { bd = dd; bi = c; }
            }
        }
        #pragma unroll
        for (int off = 32; off > 0; off >>= 1) {
            float od = __shfl_xor(bd, off, 64);
            int   oi = __shfl_xor(bi, off, 64);
            if (od < bd || (od == bd && oi < bi)) { bd = od; bi = oi; }
        }
        if (lane == 0) { ws_idx[t] = bi; out_idx[t] = (float)bi; }
    }
}

// per-token: gather quantized row, commitment partial (per-BLOCK), counts.
__global__ void quantize_kernel(const float* __restrict__ z, const float* __restrict__ cb,
                                const int* __restrict__ ws_idx,
                                float* __restrict__ out_q,
                                float* __restrict__ counts, float* __restrict__ psum) {
    __shared__ float sm[4];
    int t = (blockIdx.x * blockDim.x + threadIdx.x) >> 6;
    int lane = threadIdx.x & 63, wv = threadIdx.x >> 6;
    int k = ws_idx[t];
    const float* zr = z + (size_t)t * DDIM;
    const float* cr = cb + (size_t)k * DDIM;
    float* qr = out_q + (size_t)t * DDIM;
    float s = 0.f;
    #pragma unroll
    for (int r = 0; r < 6; r++) {
        int d = lane + 64 * r;
        float zv = zr[d];
        float qv = cr[d];
        qr[d] = qv;
        float df = zv - qv;
        s += df * df;
    }
    #pragma unroll
    for (int off = 32; off > 0; off >>= 1) s += __shfl_down(s, off, 64);
    if (lane == 0) {
        sm[wv] = s;
        atomicAdd(counts + k, 1.0f);
    }
    __syncthreads();
    if (threadIdx.x == 0) psum[blockIdx.x] = sm[0] + sm[1] + sm[2] + sm[3];
}

// single-block exclusive prefix scan of counts -> offsets (and fill cursors)
__global__ void scan_kernel(const float* __restrict__ counts,
                            int* __restrict__ offs, int* __restrict__ curs) {
    __shared__ int ps[1024];
    const int t = threadIdx.x;
    const int base = t * 8;
    int loc[8]; int s = 0;
    #pragma unroll
    for (int i = 0; i < 8; i++) { int c = (int)(counts[base + i] + 0.5f); loc[i] = s; s += c; }
    ps[t] = s;
    __syncthreads();
    for (int off = 1; off < 1024; off <<= 1) {
        int v = ps[t];
        int add = (t >= off) ? ps[t - off] : 0;
        __syncthreads();
        ps[t] = v + add;
        __syncthreads();
    }
    int excl = (t == 0) ? 0 : ps[t - 1];
    #pragma unroll
    for (int i = 0; i < 8; i++) {
        int o = excl + loc[i];
        offs[base + i] = o;
        curs[base + i] = o;
    }
    if (t == 1023) offs[KCODE] = ps[1023];
}

// bucket tokens by code (16K scattered atomics total)
__global__ void fill_kernel(const int* __restrict__ ws_idx,
                            int* __restrict__ curs, int* __restrict__ toklist) {
    int t = blockIdx.x * blockDim.x + threadIdx.x;
    if (t >= N_TOK) return;
    int k = ws_idx[t];
    int slot = atomicAdd(curs + k, 1);
    toklist[slot] = t;
}

__global__ void cluster_kernel(const float* __restrict__ ema_cs, const float* __restrict__ counts,
                               float* __restrict__ out_ncs, float* __restrict__ n_acc,
                               const float* __restrict__ psum, float* __restrict__ out_loss) {
    int i = blockIdx.x * blockDim.x + threadIdx.x;
    float v = 0.f;
    if (i < KCODE) {
        v = EMA * ema_cs[i] + (1.f - EMA) * counts[i];
        out_ncs[i] = v;
    }
    __shared__ float sm[4];
    __shared__ float sm2[4];
    int lane = threadIdx.x & 63, w = threadIdx.x >> 6;
    #pragma unroll
    for (int off = 32; off > 0; off >>= 1) v += __shfl_down(v, off, 64);
    if (lane == 0) sm[w] = v;
    __syncthreads();
    if (threadIdx.x == 0) atomicAdd(n_acc, sm[0] + sm[1] + sm[2] + sm[3]);
    if (blockIdx.x == 0) {
        float s = 0.f;
        for (int j = threadIdx.x; j < 4096; j += 256) s += psum[j];
        #pragma unroll
        for (int off = 32; off > 0; off >>= 1) s += __shfl_down(s, off, 64);
        if (lane == 0) sm2[w] = s;
        __syncthreads();
        if (threadIdx.x == 0)
            out_loss[0] = 1.25f * (sm2[0] + sm2[1] + sm2[2] + sm2[3]) / (float)(N_TOK * DDIM);
    }
}

// fused per-code embed-sum + EMA + codebook update: one wave per code.
__global__ void codebook_fused_kernel(const float* __restrict__ z,
                                      const int* __restrict__ offs, const int* __restrict__ toklist,
                                      const float* __restrict__ ema_es,
                                      const float* __restrict__ ncs, const float* __restrict__ n_acc,
                                      float* __restrict__ out_es, float* __restrict__ out_cb) {
    int k = (blockIdx.x * blockDim.x + threadIdx.x) >> 6;
    int lane = threadIdx.x & 63;
    if (k >= KCODE) return;
    int o0 = offs[k], o1 = offs[k + 1];
    float sum[6] = {0.f, 0.f, 0.f, 0.f, 0.f, 0.f};
    for (int s = o0; s < o1; s++) {
        int tok = toklist[s];
        const float* zr = z + (size_t)tok * DDIM;
        #pragma unroll
        for (int r = 0; r < 6; r++) sum[r] += zr[lane + 64 * r];
    }
    float n = n_acc[0];
    float smooth = (ncs[k] + EPS_F) / (n + (float)KCODE * EPS_F) * n;
    float inv = 1.f / smooth;
    const float* er = ema_es + (size_t)k * DDIM;
    float* oes = out_es + (size_t)k * DDIM;
    float* ocb = out_cb + (size_t)k * DDIM;
    #pragma unroll
    for (int r = 0; r < 6; r++) {
        int d = lane + 64 * r;
        float es = EMA * er[d] + (1.f - EMA) * sum[r];
        oes[d] = es;
        ocb[d] = es * inv;
    }
}

extern "C" void kernel_launch(void* const* d_in, const int* in_sizes, int n_in,
                              void* d_out, int out_size, void* d_ws, size_t ws_size,
                              hipStream_t stream) {
    const float* z       = (const float*)d_in[0];
    const float* cb      = (const float*)d_in[1];
    const float* ema_cs  = (const float*)d_in[2];
    const float* ema_es  = (const float*)d_in[3];

    float* out      = (float*)d_out;
    float* out_q    = out;
    float* out_idx  = out + 6291456;
    float* out_loss = out + 6307840;
    float* out_ncs  = out + 6307841;
    float* out_es   = out + 6316033;
    float* out_cb   = out + 9461761;

    char* w = (char*)d_ws;
    float* pd1    = (float*)(w + OFF_PD1);
    int*   pi1    = (int*)  (w + OFF_PI1);
    float* pd2    = (float*)(w + OFF_PD2);
    _Float16* cbh = (_Float16*)(w + OFF_CBH);
    int*   toklist= (int*)  (w + OFF_TOKL);
    int*   offs   = (int*)  (w + OFF_OFFS);
    int*   curs   = (int*)  (w + OFF_CURS);
    float* cnorm  = (float*)(w + OFF_CNORM);
    int*   flist  = (int*)  (w + OFF_FLIST);
    int*   fcnt   = (int*)  (w + OFF_FCNT);
    int*   ws_idx = (int*)  (w + OFF_WSIDX);
    float* counts = (float*)(w + OFF_COUNTS);
    float* psum   = (float*)(w + OFF_PSUM);
    float* n_acc  = (float*)(w + OFF_NACC);
    float* fd1    = (float*)(w + OFF_FD1);

    // zh scratch lives in out_q's first 12.58 MB (out_q fully rewritten later)
    _Float16* zh = (_Float16*)out;

    hipMemsetAsync(w + OFF_FCNT, 0, 256, stream);
    hipMemsetAsync(w + OFF_COUNTS, 0, 32768 + 256, stream);  // counts + sumsq + n_acc

    // fused convert + cnorm: (N_TOK + KCODE) waves, 4 waves/block
    convert_norm_kernel<<<(N_TOK + KCODE) / 4, 256, 0, stream>>>(z, cb, zh, cbh, cnorm);

    dim3 grid_am(N_TOK / 128, KCODE / 256, 1);
    argmin16_kernel<<<grid_am, 512, 0, stream>>>(zh, cbh, cnorm, pd1, pi1, pd2);

    topmerge_kernel<<<N_TOK / 256, 256, 0, stream>>>(pd1, pi1, pd2, ws_idx, out_idx, fcnt, flist, fd1);

    // band-limited exact rescore (reads pd1 for the band test; writes ws_idx/out_idx directly)
    rescore2_kernel<<<2048, 256, 0, stream>>>(z, cb, cnorm, pd1, fd1, flist, fcnt, ws_idx, out_idx);

    // segmented EMA path (pd* dead from here; region A reused for toklist/offs/curs)
    quantize_kernel<<<N_TOK * 64 / 256, 256, 0, stream>>>(z, cb, ws_idx, out_q, counts, psum);
    scan_kernel<<<1, 1024, 0, stream>>>(counts, offs, curs);
    fill_kernel<<<N_TOK / 256, 256, 0, stream>>>(ws_idx, curs, toklist);
    cluster_kernel<<<(KCODE + 255) / 256, 256, 0, stream>>>(ema_cs, counts, out_ncs, n_acc, psum, out_loss);
    codebook_fused_kernel<<<KCODE * 64 / 256, 256, 0, stream>>>(z, offs, toklist, ema_es, out_ncs, n_acc, out_es, out_cb);
}

// Round 12
// 550.719 us; speedup vs baseline: 1.2553x; 1.0387x over previous
//
#include <hip/hip_runtime.h>
#include <math.h>

#define N_TOK 16384
#define DDIM  384
#define KCODE 8192
#define EMA   0.99f
#define EPS_F 1e-5f
#define MARGIN 0.5f
#define NB 32            // KCODE / 256 code-blocks in coarse pass

typedef _Float16 f16x8 __attribute__((ext_vector_type(8)));
typedef float    f32x4 __attribute__((ext_vector_type(4)));

// ---- ws byte offsets (total <= proven 13,041,672 B) ----
#define OFF_PD1    0UL        // [NB][N_TOK] f32 coarse best dist
#define OFF_PI1    2097152UL  // [NB][N_TOK] i32 coarse best idx
#define OFF_PFL    4194304UL  // [NB][N_TOK] i32 margin-flag (was pd2)
#define OFF_CBH    6291456UL  // [KCODE*DDIM] f16 pre-converted codebook
#define OFF_TOKL   0UL        // phase3: [N_TOK] i32 tokens bucketed by code
#define OFF_OFFS   65536UL    // phase3: [KCODE+1] i32 segment offsets
#define OFF_CURS   98560UL    // phase3: [KCODE] i32 fill cursors
// outside region A:
#define OFF_WSIDX  12582912UL // [N_TOK] i32
#define OFF_COUNTS 12648448UL // [KCODE] f32
#define OFF_SUMSQ  12681216UL // f32 (in zeroed range)
#define OFF_NACC   12681220UL // f32 (+pad to 12681472)
#define OFF_CNORM  12681472UL // [KCODE] f32
#define OFF_FLIST  12714240UL // [N_TOK] i32 flagged tokens
#define OFF_FCNT   12779776UL // i32 + pad to 12780032
#define OFF_PSUM   12780032UL // [4096] f32 per-block commitment partials -> 12796416
#define OFF_FD1    12796416UL // [N_TOK] f32 global f16-best dist per token -> 12861952

// async global->LDS, 16B per lane; dest = wave-uniform base + lane*16
typedef __attribute__((address_space(1))) const unsigned int gas_uint;
typedef __attribute__((address_space(3))) unsigned int       las_uint;
__device__ __forceinline__ void gload_lds16(const void* g, void* l) {
    __builtin_amdgcn_global_load_lds((gas_uint*)g, (las_uint*)l, 16, 0, 0);
}

// row-wise fused fp32->f16 convert (z and cb) + codebook row norms (one wave/row).
// Block 0 additionally zeroes counts/sumsq/n_acc and fcnt (replaces 2 memsets).
__global__ void convert_norm_kernel(const float* __restrict__ z, const float* __restrict__ cb,
                                    _Float16* __restrict__ zh, _Float16* __restrict__ cbh,
                                    float* __restrict__ cnorm,
                                    float* __restrict__ zero_cnts, int* __restrict__ fcnt) {
    if (blockIdx.x == 0) {
        for (int i = threadIdx.x; i < 8256; i += 256) zero_cnts[i] = 0.f;  // counts+sumsq+nacc
        if (threadIdx.x < 64) fcnt[threadIdx.x] = 0;
    }
    int row  = (blockIdx.x * blockDim.x + threadIdx.x) >> 6;
    int lane = threadIdx.x & 63;
    const float* src;
    _Float16* dst;
    bool is_cb = (row >= N_TOK);
    if (is_cb) { int k = row - N_TOK; src = cb + (size_t)k * DDIM; dst = cbh + (size_t)k * DDIM; }
    else       {                      src = z  + (size_t)row * DDIM; dst = zh + (size_t)row * DDIM; }
    float s = 0.f;
    #pragma unroll
    for (int r = 0; r < 3; r++) {
        int e = (lane + 64 * r) * 2;
        float2 v = *(const float2*)(src + e);
        s = fmaf(v.x, v.x, fmaf(v.y, v.y, s));
        _Float16 h0 = (_Float16)v.x, h1 = (_Float16)v.y;
        dst[e] = h0; dst[e + 1] = h1;
    }
    if (is_cb) {
        #pragma unroll
        for (int off = 32; off > 0; off >>= 1) s += __shfl_down(s, off, 64);
        if (lane == 0) cnorm[row - N_TOK] = s;
    }
}

// ---- coarse pass: f16 MFMA GEMM (z . c^T), per-token top-1 + margin-flag ----
// tile 128x256, BK=64 (6 iters), 8 waves, single 48KB buffer, 2 blocks/CU
// (VGPR+AGPR <= 128 via frag-register reuse + __launch_bounds__(512,4)).
// Epilogue (round-12): top-1 butterfly (2 shfls/level, no d2) + margin flag via
// __ballot: flag <=> exists code != i1 with d < d1+MARGIN  <=> old d2-d1 < MARGIN.
// Swizzle (round-2 verified): rows 128B = 8x16B chunks; slot s holds src chunk s^(r&7).
__launch_bounds__(512, 4)
__global__ void argmin16_kernel(const _Float16* __restrict__ zh, const _Float16* __restrict__ cbh,
                                const float* __restrict__ cnorm,
                                float* __restrict__ pd1, int* __restrict__ pi1,
                                int* __restrict__ pfl) {
    __shared__ _Float16 As[128 * 64];   // 16 KB (epilogue aliases this)
    __shared__ _Float16 Bs[256 * 64];   // 32 KB

    const int tid  = threadIdx.x;
    const int lane = tid & 63;
    const int wv   = tid >> 6;
    const int wy   = wv >> 2;
    const int wx   = wv & 3;
    const int m0   = blockIdx.x * 128;
    const int n0   = blockIdx.y * 256;
    const int l15  = lane & 15;
    const int l4   = lane >> 4;
    const int rsw  = l15 & 7;           // (row&7) seen by fragment reads

    f32x4 acc[4][4];
    #pragma unroll
    for (int i = 0; i < 4; i++)
        #pragma unroll
        for (int j = 0; j < 4; j++) acc[i][j] = (f32x4){0.f, 0.f, 0.f, 0.f};

    const int r8  = lane >> 3;
    const int jch = (lane & 7) ^ (r8 & 7);
    const _Float16* a_g = zh  + (size_t)(m0 + wv * 8 + r8) * DDIM + jch * 8;
    const _Float16* b_g = cbh + (size_t)(n0 + wv * 8 + r8) * DDIM + jch * 8;
    _Float16* a_d = As + wv * 512;
    _Float16* b_d = Bs + wv * 512;

    gload_lds16(a_g,                      a_d);
    gload_lds16(a_g + (size_t)64 * DDIM,  a_d + 4096);
    gload_lds16(b_g,                      b_d);
    gload_lds16(b_g + (size_t)64 * DDIM,  b_d + 4096);
    gload_lds16(b_g + (size_t)128 * DDIM, b_d + 8192);
    gload_lds16(b_g + (size_t)192 * DDIM, b_d + 12288);

    for (int it = 0; it < 6; it++) {
        __syncthreads();   // data-ready
        f16x8 af[4], bf[4];
        #pragma unroll
        for (int im = 0; im < 4; im++)
            af[im] = *(const f16x8*)(As + (wy * 64 + im * 16 + l15) * 64 + (l4 ^ rsw) * 8);
        #pragma unroll
        for (int in = 0; in < 4; in++)
            bf[in] = *(const f16x8*)(Bs + (wx * 64 + in * 16 + l15) * 64 + (l4 ^ rsw) * 8);
        #pragma unroll
        for (int im = 0; im < 4; im++)
            #pragma unroll
            for (int in = 0; in < 4; in++)
                acc[im][in] = __builtin_amdgcn_mfma_f32_16x16x32_f16(af[im], bf[in], acc[im][in], 0, 0, 0);
        #pragma unroll
        for (int im = 0; im < 4; im++)
            af[im] = *(const f16x8*)(As + (wy * 64 + im * 16 + l15) * 64 + ((4 + l4) ^ rsw) * 8);
        #pragma unroll
        for (int in = 0; in < 4; in++)
            bf[in] = *(const f16x8*)(Bs + (wx * 64 + in * 16 + l15) * 64 + ((4 + l4) ^ rsw) * 8);
        __syncthreads();   // read-done
        if (it < 5) {
            int kc = (it + 1) * 64;
            gload_lds16(a_g + kc,                      a_d);
            gload_lds16(a_g + (size_t)64 * DDIM + kc,  a_d + 4096);
            gload_lds16(b_g + kc,                      b_d);
            gload_lds16(b_g + (size_t)64 * DDIM + kc,  b_d + 4096);
            gload_lds16(b_g + (size_t)128 * DDIM + kc, b_d + 8192);
            gload_lds16(b_g + (size_t)192 * DDIM + kc, b_d + 12288);
        }
        #pragma unroll
        for (int im = 0; im < 4; im++)
            #pragma unroll
            for (int in = 0; in < 4; in++)
                acc[im][in] = __builtin_amdgcn_mfma_f32_16x16x32_f16(af[im], bf[in], acc[im][in], 0, 0, 0);
    }

    // epilogue scratch aliases As
    float* xd1 = (float*)&As[0];             // 2KB
    int*   xfl = (int*)(xd1 + 512);          // 2KB
    int*   xi1 = (int*)(xd1 + 1024);         // 2KB

    float cn[4]; int cid[4];
    #pragma unroll
    for (int in = 0; in < 4; in++) {
        cid[in] = n0 + wx * 64 + in * 16 + l15;
        cn[in] = cnorm[cid[in]];
    }
    #pragma unroll
    for (int im = 0; im < 4; im++) {
        #pragma unroll
        for (int reg = 0; reg < 4; reg++) {
            float dd[4];
            #pragma unroll
            for (int in = 0; in < 4; in++) dd[in] = cn[in] - 2.f * acc[im][in][reg];
            float d1 = dd[0]; int i1 = cid[0];
            #pragma unroll
            for (int in = 1; in < 4; in++)
                if (dd[in] < d1) { d1 = dd[in]; i1 = cid[in]; }   // cid ascending: strict < keeps lowest
            #pragma unroll
            for (int off = 1; off < 16; off <<= 1) {
                float od = __shfl_xor(d1, off, 16);
                int   oi = __shfl_xor(i1, off, 16);
                if (od < d1 || (od == d1 && oi < i1)) { d1 = od; i1 = oi; }
            }
            // margin flag: exists code != i1 with dist < d1 + MARGIN (== old d2-d1 < MARGIN)
            bool fl = false;
            #pragma unroll
            for (int in = 0; in < 4; in++) fl |= (dd[in] < d1 + MARGIN) && (cid[in] != i1);
            unsigned long long bal = __ballot(fl);
            int gf = ((bal >> (l4 * 16)) & 0xFFFFULL) != 0ULL;
            if (l15 == 0) {
                int tl = wy * 64 + im * 16 + l4 * 4 + reg;
                xd1[tl * 4 + wx] = d1; xi1[tl * 4 + wx] = i1; xfl[tl * 4 + wx] = gf;
            }
        }
    }
    __syncthreads();
    if (tid < 128) {
        float d1 = xd1[tid * 4]; int i1 = xi1[tid * 4]; int fl = xfl[tid * 4];
        #pragma unroll
        for (int x = 1; x < 4; x++) {
            float od = xd1[tid * 4 + x]; int oi = xi1[tid * 4 + x]; int ofl = xfl[tid * 4 + x];
            if (od < d1 || (od == d1 && oi < i1)) { d1 = od; i1 = oi; fl = ofl; }
        }
        // quarters have disjoint code sets: non-winner quarter best within margin -> flag
        #pragma unroll
        for (int x = 0; x < 4; x++) {
            float od = xd1[tid * 4 + x]; int oi = xi1[tid * 4 + x];
            fl |= (oi != i1 && od < d1 + MARGIN) ? 1 : 0;
        }
        size_t o = (size_t)blockIdx.y * N_TOK + m0 + tid;
        pd1[o] = d1; pi1[o] = i1; pfl[o] = fl;
    }
}

// merge 32 coarse partials per token; flag = winner's flag OR another block's best
// within margin (block code sets disjoint -> exact same predicate as old top-2 test)
__global__ void topmerge_kernel(const float* __restrict__ pd1, const int* __restrict__ pi1,
                                const int* __restrict__ pfl,
                                int* __restrict__ ws_idx, float* __restrict__ out_idx,
                                int* __restrict__ fcnt, int* __restrict__ flist,
                                float* __restrict__ fd1) {
    int t = blockIdx.x * blockDim.x + threadIdx.x;
    if (t >= N_TOK) return;
    float d1 = pd1[t]; int i1 = pi1[t]; int fl = pfl[t];
    float d2 = 3.4e38f;
    for (int nb = 1; nb < NB; nb++) {
        size_t o = (size_t)nb * N_TOK + t;
        float od1 = pd1[o]; int oi1 = pi1[o]; int ofl = pfl[o];
        if (od1 < d1 || (od1 == d1 && oi1 < i1)) { d2 = fminf(d2, d1); d1 = od1; i1 = oi1; fl = ofl; }
        else d2 = fminf(d2, od1);
    }
    ws_idx[t] = i1;
    out_idx[t] = (float)i1;
    fd1[t] = d1;
    if (fl || (d2 - d1 < MARGIN)) {
        int s = atomicAdd(fcnt, 1);
        flist[s] = t;
    }
}

// band-limited exact rescore: one WAVE per flagged token; only code-blocks whose
// coarse minimum lies within [d1, d1+MARGIN] can contain the exact argmin.
__launch_bounds__(256)
__global__ void rescore2_kernel(const float* __restrict__ z, const float* __restrict__ cb,
                                const float* __restrict__ cnorm,
                                const float* __restrict__ pd1, const float* __restrict__ fd1,
                                const int* __restrict__ flist, const int* __restrict__ fcnt,
                                int* __restrict__ ws_idx, float* __restrict__ out_idx) {
    __shared__ float zt[4 * 384];       // per-wave private z row (no cross-wave sync!)
    const int lane = threadIdx.x & 63;
    const int wv   = threadIdx.x >> 6;
    const int count = fcnt[0];
    float* zrow = zt + wv * 384;
    for (int slot = blockIdx.x * 4 + wv; slot < count; slot += 2048 * 4) {
        int t = flist[slot];
        const float* zr = z + (size_t)t * DDIM;
        #pragma unroll
        for (int r = 0; r < 6; r++) zrow[lane + 64 * r] = zr[lane + 64 * r];
        float band = fd1[t] + MARGIN;
        float bd = 3.4e38f; int bi = 0x7fffffff;
        for (int nb = 0; nb < NB; nb++) {
            if (pd1[(size_t)nb * N_TOK + t] >= band) continue;
            #pragma unroll
            for (int c4 = 0; c4 < 4; c4++) {
                int c = nb * 256 + c4 * 64 + lane;
                const float* cr = cb + (size_t)c * DDIM;
                float a = 0.f;
                for (int d4 = 0; d4 < 96; d4++) {
                    float4 cv = *(const float4*)(cr + d4 * 4);
                    float4 zv = *(const float4*)(zrow + d4 * 4);   // LDS broadcast
                    a = fmaf(zv.x, cv.x, a);
                    a = fmaf(zv.y, cv.y, a);
                    a = fmaf(zv.z, cv.z, a);
                    a = fmaf(zv.w, cv.w, a);
                }
                float dd = cnorm[c] - 2.f * a;
                if (dd < bd) { bd = dd; bi = c; }
            }
        }
        #pragma unroll
        for (int off = 32; off > 0; off >>= 1) {
            float od = __shfl_xor(bd, off, 64);
            int   oi = __shfl_xor(bi, off, 64);
            if (od < bd || (od == bd && oi < bi)) { bd = od; bi = oi; }
        }
        if (lane == 0) { ws_idx[t] = bi; out_idx[t] = (float)bi; }
    }
}

// per-token: gather quantized row, commitment partial (per-BLOCK), counts.
__global__ void quantize_kernel(const float* __restrict__ z, const float* __restrict__ cb,
                                const int* __restrict__ ws_idx,
                                float* __restrict__ out_q,
                                float* __restrict__ counts, float* __restrict__ psum) {
    __shared__ float sm[4];
    int t = (blockIdx.x * blockDim.x + threadIdx.x) >> 6;
    int lane = threadIdx.x & 63, wv = threadIdx.x >> 6;
    int k = ws_idx[t];
    const float* zr = z + (size_t)t * DDIM;
    const float* cr = cb + (size_t)k * DDIM;
    float* qr = out_q + (size_t)t * DDIM;
    float s = 0.f;
    #pragma unroll
    for (int r = 0; r < 6; r++) {
        int d = lane + 64 * r;
        float zv = zr[d];
        float qv = cr[d];
        qr[d] = qv;
        float df = zv - qv;
        s += df * df;
    }
    #pragma unroll
    for (int off = 32; off > 0; off >>= 1) s += __shfl_down(s, off, 64);
    if (lane == 0) {
        sm[wv] = s;
        atomicAdd(counts + k, 1.0f);
    }
    __syncthreads();
    if (threadIdx.x == 0) psum[blockIdx.x] = sm[0] + sm[1] + sm[2] + sm[3];
}

// single-block: prefix scan of counts -> offs/curs, PLUS fused cluster update:
// out_ncs, n (exact single-block sum, no atomics), commitment loss from psum.
__global__ void scan_cluster_kernel(const float* __restrict__ counts,
                                    const float* __restrict__ ema_cs,
                                    const float* __restrict__ psum,
                                    int* __restrict__ offs, int* __restrict__ curs,
                                    float* __restrict__ out_ncs, float* __restrict__ n_acc,
                                    float* __restrict__ out_loss) {
    __shared__ int ps[1024];
    __shared__ float red[32];
    const int t = threadIdx.x;
    const int base = t * 8;
    int loc[8]; int s = 0; float cf[8];
    #pragma unroll
    for (int i = 0; i < 8; i++) { cf[i] = counts[base + i]; int c = (int)(cf[i] + 0.5f); loc[i] = s; s += c; }
    ps[t] = s;
    __syncthreads();
    for (int off = 1; off < 1024; off <<= 1) {
        int v = ps[t];
        int add = (t >= off) ? ps[t - off] : 0;
        __syncthreads();
        ps[t] = v + add;
        __syncthreads();
    }
    int excl = (t == 0) ? 0 : ps[t - 1];
    #pragma unroll
    for (int i = 0; i < 8; i++) {
        int o = excl + loc[i];
        offs[base + i] = o;
        curs[base + i] = o;
    }
    if (t == 1023) offs[KCODE] = ps[1023];
    // fused cluster: ncs + n + loss
    float vs = 0.f;
    #pragma unroll
    for (int i = 0; i < 8; i++) {
        float v = EMA * ema_cs[base + i] + (1.f - EMA) * cf[i];
        out_ncs[base + i] = v;
        vs += v;
    }
    float ls = 0.f;
    for (int j = t; j < 4096; j += 1024) ls += psum[j];
    int lane = t & 63, w = t >> 6;
    #pragma unroll
    for (int off = 32; off > 0; off >>= 1) { vs += __shfl_down(vs, off, 64); ls += __shfl_down(ls, off, 64); }
    if (lane == 0) { red[w] = vs; red[16 + w] = ls; }
    __syncthreads();
    if (t == 0) {
        float n = 0.f, l = 0.f;
        #pragma unroll
        for (int w2 = 0; w2 < 16; w2++) { n += red[w2]; l += red[16 + w2]; }
        n_acc[0] = n;
        out_loss[0] = 1.25f * l / (float)(N_TOK * DDIM);
    }
}

// bucket tokens by code (16K scattered atomics total)
__global__ void fill_kernel(const int* __restrict__ ws_idx,
                            int* __restrict__ curs, int* __restrict__ toklist) {
    int t = blockIdx.x * blockDim.x + threadIdx.x;
    if (t >= N_TOK) return;
    int k = ws_idx[t];
    int slot = atomicAdd(curs + k, 1);
    toklist[slot] = t;
}

// fused per-code embed-sum + EMA + codebook update: one wave per code.
__global__ void codebook_fused_kernel(const float* __restrict__ z,
                                      const int* __restrict__ offs, const int* __restrict__ toklist,
                                      const float* __restrict__ ema_es,
                                      const float* __restrict__ ncs, const float* __restrict__ n_acc,
                                      float* __restrict__ out_es, float* __restrict__ out_cb) {
    int k = (blockIdx.x * blockDim.x + threadIdx.x) >> 6;
    int lane = threadIdx.x & 63;
    if (k >= KCODE) return;
    int o0 = offs[k], o1 = offs[k + 1];
    float sum[6] = {0.f, 0.f, 0.f, 0.f, 0.f, 0.f};
    for (int s = o0; s < o1; s++) {
        int tok = toklist[s];
        const float* zr = z + (size_t)tok * DDIM;
        #pragma unroll
        for (int r = 0; r < 6; r++) sum[r] += zr[lane + 64 * r];
    }
    float n = n_acc[0];
    float smooth = (ncs[k] + EPS_F) / (n + (float)KCODE * EPS_F) * n;
    float inv = 1.f / smooth;
    const float* er = ema_es + (size_t)k * DDIM;
    float* oes = out_es + (size_t)k * DDIM;
    float* ocb = out_cb + (size_t)k * DDIM;
    #pragma unroll
    for (int r = 0; r < 6; r++) {
        int d = lane + 64 * r;
        float es = EMA * er[d] + (1.f - EMA) * sum[r];
        oes[d] = es;
        ocb[d] = es * inv;
    }
}

extern "C" void kernel_launch(void* const* d_in, const int* in_sizes, int n_in,
                              void* d_out, int out_size, void* d_ws, size_t ws_size,
                              hipStream_t stream) {
    const float* z       = (const float*)d_in[0];
    const float* cb      = (const float*)d_in[1];
    const float* ema_cs  = (const float*)d_in[2];
    const float* ema_es  = (const float*)d_in[3];

    float* out      = (float*)d_out;
    float* out_q    = out;
    float* out_idx  = out + 6291456;
    float* out_loss = out + 6307840;
    float* out_ncs  = out + 6307841;
    float* out_es   = out + 6316033;
    float* out_cb   = out + 9461761;

    char* w = (char*)d_ws;
    float* pd1    = (float*)(w + OFF_PD1);
    int*   pi1    = (int*)  (w + OFF_PI1);
    int*   pfl    = (int*)  (w + OFF_PFL);
    _Float16* cbh = (_Float16*)(w + OFF_CBH);
    int*   toklist= (int*)  (w + OFF_TOKL);
    int*   offs   = (int*)  (w + OFF_OFFS);
    int*   curs   = (int*)  (w + OFF_CURS);
    float* cnorm  = (float*)(w + OFF_CNORM);
    int*   flist  = (int*)  (w + OFF_FLIST);
    int*   fcnt   = (int*)  (w + OFF_FCNT);
    int*   ws_idx = (int*)  (w + OFF_WSIDX);
    float* counts = (float*)(w + OFF_COUNTS);
    float* psum   = (float*)(w + OFF_PSUM);
    float* n_acc  = (float*)(w + OFF_NACC);
    float* fd1    = (float*)(w + OFF_FD1);

    // zh scratch lives in out_q's first 12.58 MB (out_q fully rewritten later)
    _Float16* zh = (_Float16*)out;

    // fused convert + cnorm + workspace zeroing: (N_TOK + KCODE) waves, 4/block
    convert_norm_kernel<<<(N_TOK + KCODE) / 4, 256, 0, stream>>>(z, cb, zh, cbh, cnorm, counts, fcnt);

    dim3 grid_am(N_TOK / 128, KCODE / 256, 1);
    argmin16_kernel<<<grid_am, 512, 0, stream>>>(zh, cbh, cnorm, pd1, pi1, pfl);

    topmerge_kernel<<<N_TOK / 256, 256, 0, stream>>>(pd1, pi1, pfl, ws_idx, out_idx, fcnt, flist, fd1);

    // band-limited exact rescore (reads pd1 for the band test; writes ws_idx/out_idx directly)
    rescore2_kernel<<<2048, 256, 0, stream>>>(z, cb, cnorm, pd1, fd1, flist, fcnt, ws_idx, out_idx);

    // segmented EMA path (pd* dead from here; region A reused for toklist/offs/curs)
    quantize_kernel<<<N_TOK * 64 / 256, 256, 0, stream>>>(z, cb, ws_idx, out_q, counts, psum);
    scan_cluster_kernel<<<1, 1024, 0, stream>>>(counts, ema_cs, psum, offs, curs, out_ncs, n_acc, out_loss);
    fill_kernel<<<N_TOK / 256, 256, 0, stream>>>(ws_idx, curs, toklist);
    codebook_fused_kernel<<<KCODE * 64 / 256, 256, 0, stream>>>(z, offs, toklist, ema_es, out_ncs, n_acc, out_es, out_cb);
}